// Round 4
// baseline (1304.494 us; speedup 1.0000x reference)
//
#include <hip/hip_runtime.h>

#define NRES 64
#define GRID_CELLS (NRES * NRES * NRES)
#define SLABZ 4
#define NSLABS 16
#define TPB 1024
#define MAXC 32
#define PPT 4
#define CAPTOT 12250000u          // total entry capacity (needs ~12.07M)
#define HDR_BYTES 4096
typedef unsigned long long u64;

// header layout in ws: counts[16] @0, bases[16] @64, cursor[16] @128

__device__ __forceinline__ int slab_bz_from_z(float z) {
    float zs = z * 64.0f;
    unsigned zq = (unsigned)(zs * 32768.0f + 0.5f);
    float zsq = (float)zq * (1.0f / 32768.0f);
    return (int)(zsq - 0.5f);     // zs >= 3.2 so trunc == floor
}

__global__ __launch_bounds__(TPB)
void count_kernel(const float* __restrict__ x, const float* __restrict__ xr,
                  int n, unsigned* __restrict__ counts) {
    __shared__ unsigned h[NSLABS];
    if (threadIdx.x < NSLABS) h[threadIdx.x] = 0;
    __syncthreads();
    const int g0 = blockIdx.x * (TPB * PPT) + threadIdx.x;
#pragma unroll
    for (int q = 0; q < PPT; ++q) {
        int gi = g0 + q * TPB;
        if (gi < 2 * n) {
            const float* __restrict__ p = (gi < n) ? (x + 3 * (size_t)gi)
                                                   : (xr + 3 * (size_t)(gi - n));
            int bz = slab_bz_from_z(p[2]);
            int s0 = bz >> 2;
            int s1 = (bz + 2) >> 2;
            atomicAdd(&h[s0], 1u);
            if (s1 != s0) atomicAdd(&h[s1], 1u);
        }
    }
    __syncthreads();
    if (threadIdx.x < NSLABS) atomicAdd(&counts[threadIdx.x], h[threadIdx.x]);
}

__global__ void prefix_kernel(const unsigned* __restrict__ counts,
                              unsigned* __restrict__ bases,
                              unsigned* __restrict__ cursor) {
    if (threadIdx.x == 0 && blockIdx.x == 0) {
        unsigned acc = 0;
        for (int s = 0; s < NSLABS; ++s) {
            bases[s] = acc;
            cursor[s] = acc;
            acc += counts[s];
        }
    }
}

__global__ __launch_bounds__(TPB)
void bin_fill_kernel(const float* __restrict__ x, const float* __restrict__ xr,
                     int n, unsigned* __restrict__ cursor, u64* __restrict__ bins) {
    __shared__ unsigned lcount[NSLABS];
    __shared__ unsigned lbase[NSLABS];
    if (threadIdx.x < NSLABS) lcount[threadIdx.x] = 0;
    __syncthreads();

    const int g0 = blockIdx.x * (TPB * PPT) + threadIdx.x;
    u64 ent[PPT];
    int sl0[PPT], sl1[PPT];
    unsigned of0[PPT], of1[PPT];

#pragma unroll
    for (int q = 0; q < PPT; ++q) {
        int gi = g0 + q * TPB;
        sl0[q] = -1; sl1[q] = -1; of0[q] = 0; of1[q] = 0; ent[q] = 0;
        if (gi < 2 * n) {
            const float* __restrict__ p = (gi < n) ? (x + 3 * (size_t)gi)
                                                   : (xr + 3 * (size_t)(gi - n));
            float xs = p[0] * 64.0f;
            float ys = p[1] * 64.0f;
            float zs = p[2] * 64.0f;
            unsigned xq = (unsigned)(xs * 32768.0f + 0.5f);
            unsigned yq = (unsigned)(ys * 32768.0f + 0.5f);
            unsigned zq = (unsigned)(zs * 32768.0f + 0.5f);
            u64 sgn = (gi < n) ? 0ull : 1ull;
            ent[q] = (u64)xq | ((u64)yq << 21) | ((u64)zq << 42) | (sgn << 63);
            float zsq = (float)zq * (1.0f / 32768.0f);
            int bz = (int)(zsq - 0.5f);
            int s0 = bz >> 2;
            int s1 = (bz + 2) >> 2;
            sl0[q] = s0;
            of0[q] = atomicAdd(&lcount[s0], 1u);
            if (s1 != s0) {
                sl1[q] = s1;
                of1[q] = atomicAdd(&lcount[s1], 1u);
            }
        }
    }
    __syncthreads();
    if (threadIdx.x < NSLABS)
        lbase[threadIdx.x] = atomicAdd(&cursor[threadIdx.x], lcount[threadIdx.x]);
    __syncthreads();

#pragma unroll
    for (int q = 0; q < PPT; ++q) {
        if (sl0[q] >= 0) {
            unsigned p0 = lbase[sl0[q]] + of0[q];
            if (p0 < CAPTOT) bins[p0] = ent[q];
            if (sl1[q] >= 0) {
                unsigned p1 = lbase[sl1[q]] + of1[q];
                if (p1 < CAPTOT) bins[p1] = ent[q];
            }
        }
    }
}

__global__ __launch_bounds__(TPB)
void bin_scatter_kernel(const u64* __restrict__ bins,
                        const unsigned* __restrict__ counts,
                        const unsigned* __restrict__ bases,
                        int C, float* __restrict__ partial) {
    __shared__ float tile[NRES * NRES * SLABZ];   // 64 KB
    const int slab  = blockIdx.x / C;
    const int chunk = blockIdx.x - slab * C;
    const int z0 = slab * SLABZ;

    for (int i = threadIdx.x; i < (NRES * NRES * SLABZ) / 4; i += TPB)
        reinterpret_cast<float4*>(tile)[i] = make_float4(0.f, 0.f, 0.f, 0.f);
    __syncthreads();

    unsigned cnt = counts[slab];
    if (cnt > CAPTOT) cnt = CAPTOT;
    const u64* __restrict__ b = bins + bases[slab];
    unsigned per = (cnt + (unsigned)C - 1u) / (unsigned)C;
    unsigned e0 = (unsigned)chunk * per;
    unsigned e1 = e0 + per;
    if (e1 > cnt) e1 = cnt;

    for (unsigned e = e0 + threadIdx.x; e < e1; e += TPB) {
        u64 v = b[e];
        float xs = (float)(unsigned)(v & 0x1FFFFFu) * (1.0f / 32768.0f);
        float ys = (float)(unsigned)((v >> 21) & 0x1FFFFFu) * (1.0f / 32768.0f);
        float zs = (float)(unsigned)((v >> 42) & 0x1FFFFFu) * (1.0f / 32768.0f);
        float sgn = (v >> 63) ? -1.0f : 1.0f;

        int bx = (int)(xs - 0.5f);
        int by = (int)(ys - 0.5f);
        int bz = (int)(zs - 0.5f);
        float fx = xs - (float)bx, fy = ys - (float)by, fz = zs - (float)bz;

        float wx0 = 0.5f * (1.5f - fx) * (1.5f - fx);
        float wx1 = 0.75f - (fx - 1.0f) * (fx - 1.0f);
        float wx2 = 0.5f * (fx - 0.5f) * (fx - 0.5f);
        float wy0 = 0.5f * (1.5f - fy) * (1.5f - fy);
        float wy1 = 0.75f - (fy - 1.0f) * (fy - 1.0f);
        float wy2 = 0.5f * (fy - 0.5f) * (fy - 0.5f);
        float wzv[3];
        wzv[0] = 0.5f * (1.5f - fz) * (1.5f - fz);
        wzv[1] = 0.75f - (fz - 1.0f) * (fz - 1.0f);
        wzv[2] = 0.5f * (fz - 0.5f) * (fz - 0.5f);

        float wxy[9];
        wxy[0] = sgn * wx0 * wy0; wxy[1] = sgn * wx0 * wy1; wxy[2] = sgn * wx0 * wy2;
        wxy[3] = sgn * wx1 * wy0; wxy[4] = sgn * wx1 * wy1; wxy[5] = sgn * wx1 * wy2;
        wxy[6] = sgn * wx2 * wy0; wxy[7] = sgn * wx2 * wy1; wxy[8] = sgn * wx2 * wy2;

        int base = (bx * 64 + by) * 4;
        int zlo = bz - z0;
#pragma unroll
        for (int k = 0; k < 3; ++k) {
            int zl = zlo + k;
            if ((unsigned)zl < (unsigned)SLABZ) {
                float wzk = wzv[k];
                int a = base + zl;
#pragma unroll
                for (int i2 = 0; i2 < 3; ++i2)
#pragma unroll
                    for (int j2 = 0; j2 < 3; ++j2)
                        atomicAdd(&tile[a + i2 * 256 + j2 * 4], wxy[i2 * 3 + j2] * wzk);
            }
        }
    }
    __syncthreads();

    float* __restrict__ dst = partial + (size_t)chunk * GRID_CELLS;
    for (int t = threadIdx.x; t < NRES * NRES; t += TPB) {
        float4 v = *reinterpret_cast<const float4*>(&tile[t * 4]);
        *reinterpret_cast<float4*>(&dst[t * 64 + z0]) = v;
    }
}

// ---------------- fallback path (round-2 kernel, verified correct) --------

__global__ __launch_bounds__(TPB)
void slab_scatter_kernel(const float* __restrict__ x,
                         const float* __restrict__ xr,
                         int n, int C, float* __restrict__ partial) {
    __shared__ float tile[NRES * NRES * SLABZ];
    const int slab  = blockIdx.x / C;
    const int chunk = blockIdx.x - slab * C;
    const int z0 = slab * SLABZ;

    for (int i = threadIdx.x; i < NRES * NRES * SLABZ; i += TPB) tile[i] = 0.0f;
    __syncthreads();

    const int per = (n + C - 1) / C;
    const int p0 = chunk * per;
    const int p1 = min(n, p0 + per);

    for (int f = 0; f < 2; ++f) {
        const float* __restrict__ p = f ? xr : x;
        const float sgn = f ? -1.0f : 1.0f;
        for (int i = p0 + (int)threadIdx.x; i < p1; i += TPB) {
            float zs = p[3 * i + 2] * 64.0f;
            int bz = (int)floorf(zs - 0.5f);
            int zlo = bz - z0;
            if (zlo > SLABZ - 1 || zlo + 2 < 0) continue;

            float xs = p[3 * i + 0] * 64.0f;
            float ys = p[3 * i + 1] * 64.0f;
            int bx = (int)floorf(xs - 0.5f);
            int by = (int)floorf(ys - 0.5f);
            float fx = xs - (float)bx, fy = ys - (float)by, fz = zs - (float)bz;

            float wx0 = 0.5f * (1.5f - fx) * (1.5f - fx);
            float wx1 = 0.75f - (fx - 1.0f) * (fx - 1.0f);
            float wx2 = 0.5f * (fx - 0.5f) * (fx - 0.5f);
            float wy0 = 0.5f * (1.5f - fy) * (1.5f - fy);
            float wy1 = 0.75f - (fy - 1.0f) * (fy - 1.0f);
            float wy2 = 0.5f * (fy - 0.5f) * (fy - 0.5f);
            float wzv[3];
            wzv[0] = 0.5f * (1.5f - fz) * (1.5f - fz);
            wzv[1] = 0.75f - (fz - 1.0f) * (fz - 1.0f);
            wzv[2] = 0.5f * (fz - 0.5f) * (fz - 0.5f);

            float wxy[9];
            wxy[0] = sgn * wx0 * wy0; wxy[1] = sgn * wx0 * wy1; wxy[2] = sgn * wx0 * wy2;
            wxy[3] = sgn * wx1 * wy0; wxy[4] = sgn * wx1 * wy1; wxy[5] = sgn * wx1 * wy2;
            wxy[6] = sgn * wx2 * wy0; wxy[7] = sgn * wx2 * wy1; wxy[8] = sgn * wx2 * wy2;

            int base = (bx * 64 + by) * 4;
#pragma unroll
            for (int k = 0; k < 3; ++k) {
                int zl = zlo + k;
                if (zl < 0 || zl >= SLABZ) continue;
                float wzk = wzv[k];
                int a = base + zl;
#pragma unroll
                for (int i2 = 0; i2 < 3; ++i2)
#pragma unroll
                    for (int j2 = 0; j2 < 3; ++j2)
                        atomicAdd(&tile[a + i2 * 256 + j2 * 4], wxy[i2 * 3 + j2] * wzk);
            }
        }
    }
    __syncthreads();

    float* __restrict__ dst = partial + (size_t)chunk * GRID_CELLS;
    for (int t = threadIdx.x; t < NRES * NRES; t += TPB) {
        float4 v = *reinterpret_cast<const float4*>(&tile[t * 4]);
        *reinterpret_cast<float4*>(&dst[t * 64 + z0]) = v;
    }
}

// ---------------- shared reduce -------------------------------------------

__global__ void reduce_kernel(const float* __restrict__ partial, int C,
                              float* __restrict__ out) {
    int cell = blockIdx.x * blockDim.x + threadIdx.x;
    float s = 0.0f;
    for (int c = 0; c < C; ++c) s += partial[(size_t)c * GRID_CELLS + cell];
    s = fabsf(s);
#pragma unroll
    for (int off = 32; off > 0; off >>= 1) s += __shfl_down(s, off, 64);
    __shared__ float wsum[4];
    int lane = threadIdx.x & 63, wid = threadIdx.x >> 6;
    if (lane == 0) wsum[wid] = s;
    __syncthreads();
    if (threadIdx.x == 0) atomicAdd(out, wsum[0] + wsum[1] + wsum[2] + wsum[3]);
}

extern "C" void kernel_launch(void* const* d_in, const int* in_sizes, int n_in,
                              void* d_out, int out_size, void* d_ws, size_t ws_size,
                              hipStream_t stream) {
    const float* x  = (const float*)d_in[0];
    const float* xr = (const float*)d_in[1];
    float* out = (float*)d_out;
    char* ws = (char*)d_ws;

    int n = in_sizes[0] / 3;  // 4,000,000

    const size_t binsBytes = (size_t)CAPTOT * sizeof(u64);   // ~98 MB
    const size_t gridBytes = (size_t)GRID_CELLS * sizeof(float);  // 1 MB

    hipMemsetAsync(out, 0, sizeof(float), stream);

    if (ws_size >= HDR_BYTES + binsBytes + gridBytes) {
        unsigned* counts = (unsigned*)ws;
        unsigned* bases  = (unsigned*)(ws + 64);
        unsigned* cursor = (unsigned*)(ws + 128);
        u64* bins = (u64*)(ws + HDR_BYTES);
        float* partial = (float*)(ws + HDR_BYTES + binsBytes);
        int C = (int)((ws_size - HDR_BYTES - binsBytes) / gridBytes);
        if (C > MAXC) C = MAXC;

        hipMemsetAsync(ws, 0, HDR_BYTES, stream);

        int fillBlocks = (2 * n + TPB * PPT - 1) / (TPB * PPT);
        count_kernel<<<fillBlocks, TPB, 0, stream>>>(x, xr, n, counts);
        prefix_kernel<<<1, 64, 0, stream>>>(counts, bases, cursor);
        bin_fill_kernel<<<fillBlocks, TPB, 0, stream>>>(x, xr, n, cursor, bins);
        bin_scatter_kernel<<<NSLABS * C, TPB, 0, stream>>>(bins, counts, bases, C, partial);
        reduce_kernel<<<GRID_CELLS / 256, 256, 0, stream>>>(partial, C, out);
    } else {
        float* partial = (float*)ws;
        int C = (int)(ws_size / gridBytes);
        if (C > MAXC) C = MAXC;
        if (C < 1) C = 1;
        slab_scatter_kernel<<<NSLABS * C, TPB, 0, stream>>>(x, xr, n, C, partial);
        reduce_kernel<<<GRID_CELLS / 256, 256, 0, stream>>>(partial, C, out);
    }
}

// Round 5
// 266.862 us; speedup vs baseline: 4.8883x; 4.8883x over previous
//
#include <hip/hip_runtime.h>

#define NRES 64
#define GRID_CELLS (NRES * NRES * NRES)
#define SLABZ 4
#define NSLABS 16
#define G_CHUNKS 32
#define TILE_CELLS (NRES * NRES * SLABZ)   // 16384
#define TPB 1024
#define PPT 4
#define NBINS 64
#define CAPTOT 8100000u
#define HDR_BYTES 4096
#define MAXC 32
#define FXS 4194304.0f            // 2^22 fixed-point scale
#define INV_FXS (1.0f / 4194304.0f)
typedef unsigned long long u64;

// ws header: counts[64] @0, bases[65] @512, cursor[64] @1024

__device__ __forceinline__ unsigned quant_z(float z) {
    return (unsigned)(z * 64.0f * 32768.0f + 0.5f);
}
__device__ __forceinline__ int bz_from_zq(unsigned zq) {
    float zsq = (float)zq * (1.0f / 32768.0f);
    return (int)(zsq - 0.5f);     // zs >= 3.2 so trunc == floor
}

__global__ __launch_bounds__(TPB)
void count_kernel(const float* __restrict__ x, const float* __restrict__ xr,
                  int n, unsigned* __restrict__ counts) {
    __shared__ unsigned h[NBINS];
    if (threadIdx.x < NBINS) h[threadIdx.x] = 0;
    __syncthreads();
    const int g0 = blockIdx.x * (TPB * PPT) + threadIdx.x;
#pragma unroll
    for (int q = 0; q < PPT; ++q) {
        int gi = g0 + q * TPB;
        if (gi < 2 * n) {
            const float* __restrict__ p = (gi < n) ? (x + 3 * (size_t)gi)
                                                   : (xr + 3 * (size_t)(gi - n));
            int bz = bz_from_zq(quant_z(p[2]));
            atomicAdd(&h[bz], 1u);
        }
    }
    __syncthreads();
    if (threadIdx.x < NBINS && h[threadIdx.x]) atomicAdd(&counts[threadIdx.x], h[threadIdx.x]);
}

__global__ void prefix_kernel(const unsigned* __restrict__ counts,
                              unsigned* __restrict__ bases,
                              unsigned* __restrict__ cursor) {
    if (threadIdx.x == 0 && blockIdx.x == 0) {
        unsigned acc = 0;
        for (int b = 0; b < NBINS; ++b) {
            bases[b] = acc;
            cursor[b] = acc;
            acc += counts[b];
        }
        bases[NBINS] = acc;
    }
}

__global__ __launch_bounds__(TPB)
void bin_fill_kernel(const float* __restrict__ x, const float* __restrict__ xr,
                     int n, unsigned* __restrict__ cursor, u64* __restrict__ bins) {
    __shared__ unsigned lcount[NBINS];
    __shared__ unsigned lbase[NBINS];
    if (threadIdx.x < NBINS) lcount[threadIdx.x] = 0;
    __syncthreads();

    const int g0 = blockIdx.x * (TPB * PPT) + threadIdx.x;
    u64 ent[PPT];
    int bzq[PPT];
    unsigned ofs[PPT];

#pragma unroll
    for (int q = 0; q < PPT; ++q) {
        int gi = g0 + q * TPB;
        bzq[q] = -1; ofs[q] = 0; ent[q] = 0;
        if (gi < 2 * n) {
            const float* __restrict__ p = (gi < n) ? (x + 3 * (size_t)gi)
                                                   : (xr + 3 * (size_t)(gi - n));
            unsigned xq = (unsigned)(p[0] * 64.0f * 32768.0f + 0.5f);
            unsigned yq = (unsigned)(p[1] * 64.0f * 32768.0f + 0.5f);
            unsigned zq = quant_z(p[2]);
            u64 sgn = (gi < n) ? 0ull : 1ull;
            ent[q] = (u64)xq | ((u64)yq << 21) | ((u64)zq << 42) | (sgn << 63);
            int bz = bz_from_zq(zq);
            bzq[q] = bz;
            ofs[q] = atomicAdd(&lcount[bz], 1u);
        }
    }
    __syncthreads();
    if (threadIdx.x < NBINS)
        lbase[threadIdx.x] = lcount[threadIdx.x]
                           ? atomicAdd(&cursor[threadIdx.x], lcount[threadIdx.x]) : 0u;
    __syncthreads();

#pragma unroll
    for (int q = 0; q < PPT; ++q) {
        if (bzq[q] >= 0) {
            unsigned pos = lbase[bzq[q]] + ofs[q];
            if (pos < CAPTOT) bins[pos] = ent[q];
        }
    }
}

__global__ __launch_bounds__(TPB)
void bin_scatter_kernel(const u64* __restrict__ bins,
                        const unsigned* __restrict__ bases,
                        int* __restrict__ partial) {
    __shared__ int tile[TILE_CELLS];   // 64 KB fixed-point accumulators
    const int slab  = blockIdx.x / G_CHUNKS;
    const int chunk = blockIdx.x - slab * G_CHUNKS;
    const int z0 = slab * SLABZ;

    for (int i = threadIdx.x; i < TILE_CELLS / 4; i += TPB)
        reinterpret_cast<int4*>(tile)[i] = make_int4(0, 0, 0, 0);
    __syncthreads();

    // entries touching slab: bz in [4s-2, 4s+3]
    int begBin = 4 * slab - 2; if (begBin < 0) begBin = 0;
    int endBin = 4 * slab + 4; if (endBin > NBINS) endBin = NBINS;
    unsigned lo = bases[begBin];
    unsigned hi = bases[endBin];
    unsigned cnt = hi - lo;
    unsigned per = (cnt + (unsigned)G_CHUNKS - 1u) / (unsigned)G_CHUNKS;
    unsigned e0 = lo + (unsigned)chunk * per;
    unsigned e1 = e0 + per;
    if (e1 > hi) e1 = hi;

    for (unsigned e = e0 + threadIdx.x; e < e1; e += TPB) {
        u64 v = bins[e];
        float xs = (float)(unsigned)(v & 0x1FFFFFu) * (1.0f / 32768.0f);
        float ys = (float)(unsigned)((v >> 21) & 0x1FFFFFu) * (1.0f / 32768.0f);
        float zs = (float)(unsigned)((v >> 42) & 0x1FFFFFu) * (1.0f / 32768.0f);
        float sgn = (v >> 63) ? -1.0f : 1.0f;

        int bx = (int)(xs - 0.5f);
        int by = (int)(ys - 0.5f);
        int bz = (int)(zs - 0.5f);
        float fx = xs - (float)bx, fy = ys - (float)by, fz = zs - (float)bz;

        float wx0 = 0.5f * (1.5f - fx) * (1.5f - fx);
        float wx1 = 0.75f - (fx - 1.0f) * (fx - 1.0f);
        float wx2 = 0.5f * (fx - 0.5f) * (fx - 0.5f);
        float wy0 = 0.5f * (1.5f - fy) * (1.5f - fy);
        float wy1 = 0.75f - (fy - 1.0f) * (fy - 1.0f);
        float wy2 = 0.5f * (fy - 0.5f) * (fy - 0.5f);
        float wzv[3];
        wzv[0] = 0.5f * (1.5f - fz) * (1.5f - fz);
        wzv[1] = 0.75f - (fz - 1.0f) * (fz - 1.0f);
        wzv[2] = 0.5f * (fz - 0.5f) * (fz - 0.5f);

        float wxy[9];
        wxy[0] = sgn * wx0 * wy0; wxy[1] = sgn * wx0 * wy1; wxy[2] = sgn * wx0 * wy2;
        wxy[3] = sgn * wx1 * wy0; wxy[4] = sgn * wx1 * wy1; wxy[5] = sgn * wx1 * wy2;
        wxy[6] = sgn * wx2 * wy0; wxy[7] = sgn * wx2 * wy1; wxy[8] = sgn * wx2 * wy2;

        int base = (bx * 64 + by) * 4;
        int zlo = bz - z0;
#pragma unroll
        for (int k = 0; k < 3; ++k) {
            int zl = zlo + k;
            if ((unsigned)zl < (unsigned)SLABZ) {
                float wzS = wzv[k] * FXS;
                int a = base + zl;
#pragma unroll
                for (int i2 = 0; i2 < 3; ++i2)
#pragma unroll
                    for (int j2 = 0; j2 < 3; ++j2)
                        atomicAdd(&tile[a + i2 * 256 + j2 * 4],
                                  __float2int_rn(wxy[i2 * 3 + j2] * wzS));
            }
        }
    }
    __syncthreads();

    int* __restrict__ dst = partial + (size_t)blockIdx.x * TILE_CELLS;
    for (int i = threadIdx.x; i < TILE_CELLS / 4; i += TPB)
        reinterpret_cast<int4*>(dst)[i] = reinterpret_cast<const int4*>(tile)[i];
}

__global__ void int_reduce_kernel(const int* __restrict__ partial,
                                  float* __restrict__ out) {
    int tid = blockIdx.x * blockDim.x + threadIdx.x;   // 0 .. 262143
    int s  = tid >> 14;          // slab
    int ti = tid & 16383;        // tile cell
    const int* __restrict__ p = partial + ((size_t)s * G_CHUNKS) * TILE_CELLS + ti;
    int sum = 0;
#pragma unroll 8
    for (int g = 0; g < G_CHUNKS; ++g) sum += p[(size_t)g * TILE_CELLS];
    float v = fabsf((float)sum) * INV_FXS;
#pragma unroll
    for (int off = 32; off > 0; off >>= 1) v += __shfl_down(v, off, 64);
    __shared__ float wsum[4];
    int lane = threadIdx.x & 63, wid = threadIdx.x >> 6;
    if (lane == 0) wsum[wid] = v;
    __syncthreads();
    if (threadIdx.x == 0) atomicAdd(out, wsum[0] + wsum[1] + wsum[2] + wsum[3]);
}

// ---------------- fallback path (round-2 kernels, verified correct) --------

__global__ __launch_bounds__(TPB)
void slab_scatter_kernel(const float* __restrict__ x,
                         const float* __restrict__ xr,
                         int n, int C, float* __restrict__ partial) {
    __shared__ float tile[TILE_CELLS];
    const int slab  = blockIdx.x / C;
    const int chunk = blockIdx.x - slab * C;
    const int z0 = slab * SLABZ;

    for (int i = threadIdx.x; i < TILE_CELLS; i += TPB) tile[i] = 0.0f;
    __syncthreads();

    const int per = (n + C - 1) / C;
    const int p0 = chunk * per;
    const int p1 = min(n, p0 + per);

    for (int f = 0; f < 2; ++f) {
        const float* __restrict__ p = f ? xr : x;
        const float sgn = f ? -1.0f : 1.0f;
        for (int i = p0 + (int)threadIdx.x; i < p1; i += TPB) {
            float zs = p[3 * i + 2] * 64.0f;
            int bz = (int)floorf(zs - 0.5f);
            int zlo = bz - z0;
            if (zlo > SLABZ - 1 || zlo + 2 < 0) continue;

            float xs = p[3 * i + 0] * 64.0f;
            float ys = p[3 * i + 1] * 64.0f;
            int bx = (int)floorf(xs - 0.5f);
            int by = (int)floorf(ys - 0.5f);
            float fx = xs - (float)bx, fy = ys - (float)by, fz = zs - (float)bz;

            float wx0 = 0.5f * (1.5f - fx) * (1.5f - fx);
            float wx1 = 0.75f - (fx - 1.0f) * (fx - 1.0f);
            float wx2 = 0.5f * (fx - 0.5f) * (fx - 0.5f);
            float wy0 = 0.5f * (1.5f - fy) * (1.5f - fy);
            float wy1 = 0.75f - (fy - 1.0f) * (fy - 1.0f);
            float wy2 = 0.5f * (fy - 0.5f) * (fy - 0.5f);
            float wzv[3];
            wzv[0] = 0.5f * (1.5f - fz) * (1.5f - fz);
            wzv[1] = 0.75f - (fz - 1.0f) * (fz - 1.0f);
            wzv[2] = 0.5f * (fz - 0.5f) * (fz - 0.5f);

            float wxy[9];
            wxy[0] = sgn * wx0 * wy0; wxy[1] = sgn * wx0 * wy1; wxy[2] = sgn * wx0 * wy2;
            wxy[3] = sgn * wx1 * wy0; wxy[4] = sgn * wx1 * wy1; wxy[5] = sgn * wx1 * wy2;
            wxy[6] = sgn * wx2 * wy0; wxy[7] = sgn * wx2 * wy1; wxy[8] = sgn * wx2 * wy2;

            int base = (bx * 64 + by) * 4;
#pragma unroll
            for (int k = 0; k < 3; ++k) {
                int zl = zlo + k;
                if (zl < 0 || zl >= SLABZ) continue;
                float wzk = wzv[k];
                int a = base + zl;
#pragma unroll
                for (int i2 = 0; i2 < 3; ++i2)
#pragma unroll
                    for (int j2 = 0; j2 < 3; ++j2)
                        atomicAdd(&tile[a + i2 * 256 + j2 * 4], wxy[i2 * 3 + j2] * wzk);
            }
        }
    }
    __syncthreads();

    float* __restrict__ dst = partial + (size_t)chunk * GRID_CELLS;
    for (int t = threadIdx.x; t < NRES * NRES; t += TPB) {
        float4 v = *reinterpret_cast<const float4*>(&tile[t * 4]);
        *reinterpret_cast<float4*>(&dst[t * 64 + z0]) = v;
    }
}

__global__ void reduce_kernel(const float* __restrict__ partial, int C,
                              float* __restrict__ out) {
    int cell = blockIdx.x * blockDim.x + threadIdx.x;
    float s = 0.0f;
    for (int c = 0; c < C; ++c) s += partial[(size_t)c * GRID_CELLS + cell];
    s = fabsf(s);
#pragma unroll
    for (int off = 32; off > 0; off >>= 1) s += __shfl_down(s, off, 64);
    __shared__ float wsum[4];
    int lane = threadIdx.x & 63, wid = threadIdx.x >> 6;
    if (lane == 0) wsum[wid] = s;
    __syncthreads();
    if (threadIdx.x == 0) atomicAdd(out, wsum[0] + wsum[1] + wsum[2] + wsum[3]);
}

extern "C" void kernel_launch(void* const* d_in, const int* in_sizes, int n_in,
                              void* d_out, int out_size, void* d_ws, size_t ws_size,
                              hipStream_t stream) {
    const float* x  = (const float*)d_in[0];
    const float* xr = (const float*)d_in[1];
    float* out = (float*)d_out;
    char* ws = (char*)d_ws;

    int n = in_sizes[0] / 3;  // 4,000,000

    const size_t binsBytes = (size_t)CAPTOT * sizeof(u64);                    // 64.8 MB
    const size_t partBytes = (size_t)NSLABS * G_CHUNKS * TILE_CELLS * 4;      // 32 MB
    const size_t gridBytes = (size_t)GRID_CELLS * sizeof(float);              // 1 MB

    hipMemsetAsync(out, 0, sizeof(float), stream);

    if (ws_size >= HDR_BYTES + binsBytes + partBytes) {
        unsigned* counts = (unsigned*)ws;
        unsigned* bases  = (unsigned*)(ws + 512);
        unsigned* cursor = (unsigned*)(ws + 1024);
        u64* bins = (u64*)(ws + HDR_BYTES);
        int* partial = (int*)(ws + HDR_BYTES + binsBytes);

        hipMemsetAsync(ws, 0, HDR_BYTES, stream);

        int fillBlocks = (2 * n + TPB * PPT - 1) / (TPB * PPT);
        count_kernel<<<fillBlocks, TPB, 0, stream>>>(x, xr, n, counts);
        prefix_kernel<<<1, 64, 0, stream>>>(counts, bases, cursor);
        bin_fill_kernel<<<fillBlocks, TPB, 0, stream>>>(x, xr, n, cursor, bins);
        bin_scatter_kernel<<<NSLABS * G_CHUNKS, TPB, 0, stream>>>(bins, bases, partial);
        int_reduce_kernel<<<GRID_CELLS / 256, 256, 0, stream>>>(partial, out);
    } else {
        float* partial = (float*)ws;
        int C = (int)(ws_size / gridBytes);
        if (C > MAXC) C = MAXC;
        if (C < 1) C = 1;
        slab_scatter_kernel<<<NSLABS * C, TPB, 0, stream>>>(x, xr, n, C, partial);
        reduce_kernel<<<GRID_CELLS / 256, 256, 0, stream>>>(partial, C, out);
    }
}

// Round 6
// 207.136 us; speedup vs baseline: 6.2978x; 1.2883x over previous
//
#include <hip/hip_runtime.h>

#define NRES 64
#define GRID_CELLS (NRES * NRES * NRES)
#define SLABZ 4
#define NSLABS 16
#define G_CHUNKS 32
#define TILE_CELLS (NRES * NRES * SLABZ)   // 16384
#define TPB 1024
#define PPT 4
#define NBINS 64
#define CAPTOT 8100000u
#define HDR_BYTES 4096
#define MAXC 32
#define FXS 4194304.0f            // 2^22 fixed-point scale
#define INV_FXS (1.0f / 4194304.0f)
typedef unsigned long long u64;

// ws header: counts[64] @0, bases[65] @512, cursor[64] @1024

__device__ __forceinline__ unsigned quant_z(float z) {
    return (unsigned)(z * 64.0f * 32768.0f + 0.5f);
}
__device__ __forceinline__ int bz_from_zq(unsigned zq) {
    float zsq = (float)zq * (1.0f / 32768.0f);
    return (int)(zsq - 0.5f);     // zs >= 3.2 so trunc == floor
}

__global__ __launch_bounds__(TPB)
void count_kernel(const float* __restrict__ x, const float* __restrict__ xr,
                  int n, unsigned* __restrict__ counts) {
    __shared__ unsigned h[NBINS];
    if (threadIdx.x < NBINS) h[threadIdx.x] = 0;
    __syncthreads();
    const int g0 = blockIdx.x * (TPB * PPT) + threadIdx.x;
#pragma unroll
    for (int q = 0; q < PPT; ++q) {
        int gi = g0 + q * TPB;
        if (gi < 2 * n) {
            const float* __restrict__ p = (gi < n) ? (x + 3 * (size_t)gi)
                                                   : (xr + 3 * (size_t)(gi - n));
            int bz = bz_from_zq(quant_z(p[2]));
            atomicAdd(&h[bz], 1u);
        }
    }
    __syncthreads();
    if (threadIdx.x < NBINS && h[threadIdx.x]) atomicAdd(&counts[threadIdx.x], h[threadIdx.x]);
}

__global__ void prefix_kernel(const unsigned* __restrict__ counts,
                              unsigned* __restrict__ bases,
                              unsigned* __restrict__ cursor) {
    if (threadIdx.x == 0 && blockIdx.x == 0) {
        unsigned acc = 0;
        for (int b = 0; b < NBINS; ++b) {
            bases[b] = acc;
            cursor[b] = acc;
            acc += counts[b];
        }
        bases[NBINS] = acc;
    }
}

__global__ __launch_bounds__(TPB)
void bin_fill_kernel(const float* __restrict__ x, const float* __restrict__ xr,
                     int n, unsigned* __restrict__ cursor, u64* __restrict__ bins) {
    __shared__ unsigned lcount[NBINS];
    __shared__ unsigned lbase[NBINS];
    if (threadIdx.x < NBINS) lcount[threadIdx.x] = 0;
    __syncthreads();

    const int g0 = blockIdx.x * (TPB * PPT) + threadIdx.x;
    u64 ent[PPT];
    int bzq[PPT];
    unsigned ofs[PPT];

#pragma unroll
    for (int q = 0; q < PPT; ++q) {
        int gi = g0 + q * TPB;
        bzq[q] = -1; ofs[q] = 0; ent[q] = 0;
        if (gi < 2 * n) {
            const float* __restrict__ p = (gi < n) ? (x + 3 * (size_t)gi)
                                                   : (xr + 3 * (size_t)(gi - n));
            unsigned xq = (unsigned)(p[0] * 64.0f * 32768.0f + 0.5f);
            unsigned yq = (unsigned)(p[1] * 64.0f * 32768.0f + 0.5f);
            unsigned zq = quant_z(p[2]);
            u64 sgn = (gi < n) ? 0ull : 1ull;
            ent[q] = (u64)xq | ((u64)yq << 21) | ((u64)zq << 42) | (sgn << 63);
            int bz = bz_from_zq(zq);
            bzq[q] = bz;
            ofs[q] = atomicAdd(&lcount[bz], 1u);
        }
    }
    __syncthreads();
    if (threadIdx.x < NBINS)
        lbase[threadIdx.x] = lcount[threadIdx.x]
                           ? atomicAdd(&cursor[threadIdx.x], lcount[threadIdx.x]) : 0u;
    __syncthreads();

#pragma unroll
    for (int q = 0; q < PPT; ++q) {
        if (bzq[q] >= 0) {
            unsigned pos = lbase[bzq[q]] + ofs[q];
            if (pos < CAPTOT) bins[pos] = ent[q];
        }
    }
}

// tile layout: idx = zl*4096 + bx*64 + by  (z-plane-major)
// bank = (by + j2) % 32 per instruction -> conflict-free for random by
__global__ __launch_bounds__(TPB)
void bin_scatter_kernel(const u64* __restrict__ bins,
                        const unsigned* __restrict__ bases,
                        int* __restrict__ partial) {
    __shared__ int tile[TILE_CELLS];   // 64 KB fixed-point accumulators
    const int slab  = blockIdx.x / G_CHUNKS;
    const int chunk = blockIdx.x - slab * G_CHUNKS;
    const int z0 = slab * SLABZ;

    for (int i = threadIdx.x; i < TILE_CELLS / 4; i += TPB)
        reinterpret_cast<int4*>(tile)[i] = make_int4(0, 0, 0, 0);
    __syncthreads();

    // entries touching slab: bz in [4s-2, 4s+3]
    int begBin = 4 * slab - 2; if (begBin < 0) begBin = 0;
    int endBin = 4 * slab + 4; if (endBin > NBINS) endBin = NBINS;
    unsigned lo = bases[begBin];
    unsigned hi = bases[endBin];
    unsigned cnt = hi - lo;
    unsigned per = (cnt + (unsigned)G_CHUNKS - 1u) / (unsigned)G_CHUNKS;
    unsigned e0 = lo + (unsigned)chunk * per;
    unsigned e1 = e0 + per;
    if (e1 > hi) e1 = hi;

    for (unsigned e = e0 + threadIdx.x; e < e1; e += TPB) {
        u64 v = bins[e];
        float xs = (float)(unsigned)(v & 0x1FFFFFu) * (1.0f / 32768.0f);
        float ys = (float)(unsigned)((v >> 21) & 0x1FFFFFu) * (1.0f / 32768.0f);
        float zs = (float)(unsigned)((v >> 42) & 0x1FFFFFu) * (1.0f / 32768.0f);
        float sgn = (v >> 63) ? -1.0f : 1.0f;

        int bx = (int)(xs - 0.5f);
        int by = (int)(ys - 0.5f);
        int bz = (int)(zs - 0.5f);
        float fx = xs - (float)bx, fy = ys - (float)by, fz = zs - (float)bz;

        float wx0 = 0.5f * (1.5f - fx) * (1.5f - fx);
        float wx1 = 0.75f - (fx - 1.0f) * (fx - 1.0f);
        float wx2 = 0.5f * (fx - 0.5f) * (fx - 0.5f);
        float wy0 = 0.5f * (1.5f - fy) * (1.5f - fy);
        float wy1 = 0.75f - (fy - 1.0f) * (fy - 1.0f);
        float wy2 = 0.5f * (fy - 0.5f) * (fy - 0.5f);
        float wzv[3];
        wzv[0] = 0.5f * (1.5f - fz) * (1.5f - fz);
        wzv[1] = 0.75f - (fz - 1.0f) * (fz - 1.0f);
        wzv[2] = 0.5f * (fz - 0.5f) * (fz - 0.5f);

        float wxy[9];
        wxy[0] = sgn * wx0 * wy0; wxy[1] = sgn * wx0 * wy1; wxy[2] = sgn * wx0 * wy2;
        wxy[3] = sgn * wx1 * wy0; wxy[4] = sgn * wx1 * wy1; wxy[5] = sgn * wx1 * wy2;
        wxy[6] = sgn * wx2 * wy0; wxy[7] = sgn * wx2 * wy1; wxy[8] = sgn * wx2 * wy2;

        int basexy = bx * 64 + by;
        int zlo = bz - z0;
#pragma unroll
        for (int k = 0; k < 3; ++k) {
            int zl = zlo + k;
            if ((unsigned)zl < (unsigned)SLABZ) {
                float wzS = wzv[k] * FXS;
                int a = zl * 4096 + basexy;
#pragma unroll
                for (int i2 = 0; i2 < 3; ++i2)
#pragma unroll
                    for (int j2 = 0; j2 < 3; ++j2)
                        atomicAdd(&tile[a + i2 * 64 + j2],
                                  __float2int_rn(wxy[i2 * 3 + j2] * wzS));
            }
        }
    }
    __syncthreads();

    int* __restrict__ dst = partial + (size_t)blockIdx.x * TILE_CELLS;
    for (int i = threadIdx.x; i < TILE_CELLS / 4; i += TPB)
        reinterpret_cast<int4*>(dst)[i] = reinterpret_cast<const int4*>(tile)[i];
}

__global__ void int_reduce_kernel(const int* __restrict__ partial,
                                  float* __restrict__ out) {
    int tid = blockIdx.x * blockDim.x + threadIdx.x;   // 0 .. 262143
    int s  = tid >> 14;          // slab
    int ti = tid & 16383;        // tile cell
    const int* __restrict__ p = partial + ((size_t)s * G_CHUNKS) * TILE_CELLS + ti;
    int sum = 0;
#pragma unroll 8
    for (int g = 0; g < G_CHUNKS; ++g) sum += p[(size_t)g * TILE_CELLS];
    float v = fabsf((float)sum) * INV_FXS;
#pragma unroll
    for (int off = 32; off > 0; off >>= 1) v += __shfl_down(v, off, 64);
    __shared__ float wsum[4];
    int lane = threadIdx.x & 63, wid = threadIdx.x >> 6;
    if (lane == 0) wsum[wid] = v;
    __syncthreads();
    if (threadIdx.x == 0) atomicAdd(out, wsum[0] + wsum[1] + wsum[2] + wsum[3]);
}

// ---------------- fallback path (round-2 kernels, verified correct) --------

__global__ __launch_bounds__(TPB)
void slab_scatter_kernel(const float* __restrict__ x,
                         const float* __restrict__ xr,
                         int n, int C, float* __restrict__ partial) {
    __shared__ float tile[TILE_CELLS];
    const int slab  = blockIdx.x / C;
    const int chunk = blockIdx.x - slab * C;
    const int z0 = slab * SLABZ;

    for (int i = threadIdx.x; i < TILE_CELLS; i += TPB) tile[i] = 0.0f;
    __syncthreads();

    const int per = (n + C - 1) / C;
    const int p0 = chunk * per;
    const int p1 = min(n, p0 + per);

    for (int f = 0; f < 2; ++f) {
        const float* __restrict__ p = f ? xr : x;
        const float sgn = f ? -1.0f : 1.0f;
        for (int i = p0 + (int)threadIdx.x; i < p1; i += TPB) {
            float zs = p[3 * i + 2] * 64.0f;
            int bz = (int)floorf(zs - 0.5f);
            int zlo = bz - z0;
            if (zlo > SLABZ - 1 || zlo + 2 < 0) continue;

            float xs = p[3 * i + 0] * 64.0f;
            float ys = p[3 * i + 1] * 64.0f;
            int bx = (int)floorf(xs - 0.5f);
            int by = (int)floorf(ys - 0.5f);
            float fx = xs - (float)bx, fy = ys - (float)by, fz = zs - (float)bz;

            float wx0 = 0.5f * (1.5f - fx) * (1.5f - fx);
            float wx1 = 0.75f - (fx - 1.0f) * (fx - 1.0f);
            float wx2 = 0.5f * (fx - 0.5f) * (fx - 0.5f);
            float wy0 = 0.5f * (1.5f - fy) * (1.5f - fy);
            float wy1 = 0.75f - (fy - 1.0f) * (fy - 1.0f);
            float wy2 = 0.5f * (fy - 0.5f) * (fy - 0.5f);
            float wzv[3];
            wzv[0] = 0.5f * (1.5f - fz) * (1.5f - fz);
            wzv[1] = 0.75f - (fz - 1.0f) * (fz - 1.0f);
            wzv[2] = 0.5f * (fz - 0.5f) * (fz - 0.5f);

            float wxy[9];
            wxy[0] = sgn * wx0 * wy0; wxy[1] = sgn * wx0 * wy1; wxy[2] = sgn * wx0 * wy2;
            wxy[3] = sgn * wx1 * wy0; wxy[4] = sgn * wx1 * wy1; wxy[5] = sgn * wx1 * wy2;
            wxy[6] = sgn * wx2 * wy0; wxy[7] = sgn * wx2 * wy1; wxy[8] = sgn * wx2 * wy2;

            int base = (bx * 64 + by) * 4;
#pragma unroll
            for (int k = 0; k < 3; ++k) {
                int zl = zlo + k;
                if (zl < 0 || zl >= SLABZ) continue;
                float wzk = wzv[k];
                int a = base + zl;
#pragma unroll
                for (int i2 = 0; i2 < 3; ++i2)
#pragma unroll
                    for (int j2 = 0; j2 < 3; ++j2)
                        atomicAdd(&tile[a + i2 * 256 + j2 * 4], wxy[i2 * 3 + j2] * wzk);
            }
        }
    }
    __syncthreads();

    float* __restrict__ dst = partial + (size_t)chunk * GRID_CELLS;
    for (int t = threadIdx.x; t < NRES * NRES; t += TPB) {
        float4 v = *reinterpret_cast<const float4*>(&tile[t * 4]);
        *reinterpret_cast<float4*>(&dst[t * 64 + z0]) = v;
    }
}

__global__ void reduce_kernel(const float* __restrict__ partial, int C,
                              float* __restrict__ out) {
    int cell = blockIdx.x * blockDim.x + threadIdx.x;
    float s = 0.0f;
    for (int c = 0; c < C; ++c) s += partial[(size_t)c * GRID_CELLS + cell];
    s = fabsf(s);
#pragma unroll
    for (int off = 32; off > 0; off >>= 1) s += __shfl_down(s, off, 64);
    __shared__ float wsum[4];
    int lane = threadIdx.x & 63, wid = threadIdx.x >> 6;
    if (lane == 0) wsum[wid] = s;
    __syncthreads();
    if (threadIdx.x == 0) atomicAdd(out, wsum[0] + wsum[1] + wsum[2] + wsum[3]);
}

extern "C" void kernel_launch(void* const* d_in, const int* in_sizes, int n_in,
                              void* d_out, int out_size, void* d_ws, size_t ws_size,
                              hipStream_t stream) {
    const float* x  = (const float*)d_in[0];
    const float* xr = (const float*)d_in[1];
    float* out = (float*)d_out;
    char* ws = (char*)d_ws;

    int n = in_sizes[0] / 3;  // 4,000,000

    const size_t binsBytes = (size_t)CAPTOT * sizeof(u64);                    // 64.8 MB
    const size_t partBytes = (size_t)NSLABS * G_CHUNKS * TILE_CELLS * 4;      // 32 MB
    const size_t gridBytes = (size_t)GRID_CELLS * sizeof(float);              // 1 MB

    hipMemsetAsync(out, 0, sizeof(float), stream);

    if (ws_size >= HDR_BYTES + binsBytes + partBytes) {
        unsigned* counts = (unsigned*)ws;
        unsigned* bases  = (unsigned*)(ws + 512);
        unsigned* cursor = (unsigned*)(ws + 1024);
        u64* bins = (u64*)(ws + HDR_BYTES);
        int* partial = (int*)(ws + HDR_BYTES + binsBytes);

        hipMemsetAsync(ws, 0, HDR_BYTES, stream);

        int fillBlocks = (2 * n + TPB * PPT - 1) / (TPB * PPT);
        count_kernel<<<fillBlocks, TPB, 0, stream>>>(x, xr, n, counts);
        prefix_kernel<<<1, 64, 0, stream>>>(counts, bases, cursor);
        bin_fill_kernel<<<fillBlocks, TPB, 0, stream>>>(x, xr, n, cursor, bins);
        bin_scatter_kernel<<<NSLABS * G_CHUNKS, TPB, 0, stream>>>(bins, bases, partial);
        int_reduce_kernel<<<GRID_CELLS / 256, 256, 0, stream>>>(partial, out);
    } else {
        float* partial = (float*)ws;
        int C = (int)(ws_size / gridBytes);
        if (C > MAXC) C = MAXC;
        if (C < 1) C = 1;
        slab_scatter_kernel<<<NSLABS * C, TPB, 0, stream>>>(x, xr, n, C, partial);
        reduce_kernel<<<GRID_CELLS / 256, 256, 0, stream>>>(partial, C, out);
    }
}

// Round 7
// 160.071 us; speedup vs baseline: 8.1494x; 1.2940x over previous
//
#include <hip/hip_runtime.h>

#define NRES 64
#define GRID_CELLS (NRES * NRES * NRES)
#define SLABZ 4
#define NSLABS 16
#define G_CHUNKS 32
#define TILE_CELLS (NRES * NRES * SLABZ)   // 16384
#define TPB 1024
#define NBLK 512
#define NBINS 64
#define MAXC 32
#define FXS 4194304.0f            // 2^22 fixed-point scale
#define INV_FXS (1.0f / 4194304.0f)
#define QS 2097152.0f             // 64 * 32768 position quantizer
typedef unsigned long long u64;
typedef unsigned u32;

// ws layout (main path):
//   blockCounts u32[NBINS*NBLK] @ 0        (128 KB)
//   scanned     u32[NBINS*NBLK] @ 131072   (128 KB)
//   binBases    u32[65]         @ 262144
//   binTotals   u32[64]         @ 263168
//   bins        u64[2n]         @ 266240   (64 MB for n=4M)
//   partial     int[512*16384]  @ 266240 + 16n  (32 MB)

__device__ __forceinline__ u32 quantc(float v) {
    return (u32)(v * QS + 0.5f);
}
__device__ __forceinline__ int bz_from_zq(u32 zq) {
    float zsq = (float)zq * (1.0f / 32768.0f);
    int bz = (int)(zsq - 0.5f);       // zs >= 3.2 so trunc == floor
    return min(max(bz, 0), NBINS - 1);
}

__global__ __launch_bounds__(TPB)
void count_kernel(const float* __restrict__ x, const float* __restrict__ xr,
                  int n, u32* __restrict__ blockCounts) {
    __shared__ u32 h[NBINS];
    if (threadIdx.x < NBINS) h[threadIdx.x] = 0;
    __syncthreads();
    const int Q = n >> 2;          // quads per array
    const int GQ = 2 * Q;
    for (int g = blockIdx.x * TPB + threadIdx.x; g < GQ; g += NBLK * TPB) {
        const float* __restrict__ p = (g < Q) ? (x + 12 * (size_t)g)
                                              : (xr + 12 * (size_t)(g - Q));
        float4 a = ((const float4*)p)[0];
        float4 b = ((const float4*)p)[1];
        float4 c = ((const float4*)p)[2];
        atomicAdd(&h[bz_from_zq(quantc(a.z))], 1u);
        atomicAdd(&h[bz_from_zq(quantc(b.y))], 1u);
        atomicAdd(&h[bz_from_zq(quantc(c.x))], 1u);
        atomicAdd(&h[bz_from_zq(quantc(c.w))], 1u);
    }
    __syncthreads();
    if (threadIdx.x < NBINS)
        blockCounts[threadIdx.x * NBLK + blockIdx.x] = h[threadIdx.x];
}

__global__ __launch_bounds__(NBLK)
void scanA_kernel(const u32* __restrict__ blockCounts,
                  u32* __restrict__ scanned, u32* __restrict__ binTotals) {
    __shared__ u32 s[NBLK];
    const int b = blockIdx.x, t = threadIdx.x;
    u32 v = blockCounts[b * NBLK + t];
    s[t] = v;
    __syncthreads();
    for (int off = 1; off < NBLK; off <<= 1) {
        u32 add = (t >= off) ? s[t - off] : 0u;
        __syncthreads();
        s[t] += add;
        __syncthreads();
    }
    scanned[b * NBLK + t] = s[t] - v;     // exclusive
    if (t == NBLK - 1) binTotals[b] = s[t];
}

__global__ void scanB_kernel(const u32* __restrict__ binTotals,
                             u32* __restrict__ binBases) {
    if (threadIdx.x == 0 && blockIdx.x == 0) {
        u32 acc = 0;
        for (int i = 0; i < NBINS; ++i) { binBases[i] = acc; acc += binTotals[i]; }
        binBases[NBINS] = acc;
    }
}

__global__ __launch_bounds__(TPB)
void fill_kernel(const float* __restrict__ x, const float* __restrict__ xr,
                 int n, const u32* __restrict__ scanned,
                 const u32* __restrict__ binBases, u64* __restrict__ bins) {
    __shared__ u32 cur[NBINS];
    if (threadIdx.x < NBINS)
        cur[threadIdx.x] = binBases[threadIdx.x]
                         + scanned[threadIdx.x * NBLK + blockIdx.x];
    __syncthreads();
    const int Q = n >> 2;
    const int GQ = 2 * Q;
    const u32 cap = (u32)(2 * n);
    for (int g = blockIdx.x * TPB + threadIdx.x; g < GQ; g += NBLK * TPB) {
        int inx = (g < Q);
        const float* __restrict__ p = inx ? (x + 12 * (size_t)g)
                                          : (xr + 12 * (size_t)(g - Q));
        float4 a = ((const float4*)p)[0];
        float4 b = ((const float4*)p)[1];
        float4 c = ((const float4*)p)[2];
        u64 sgn = inx ? 0ull : (1ull << 63);
        float px[4] = {a.x, a.w, b.z, c.y};
        float py[4] = {a.y, b.x, b.w, c.z};
        float pz[4] = {a.z, b.y, c.x, c.w};
#pragma unroll
        for (int q = 0; q < 4; ++q) {
            u32 xq = quantc(px[q]);
            u32 yq = quantc(py[q]);
            u32 zq = quantc(pz[q]);
            u64 ent = (u64)xq | ((u64)yq << 21) | ((u64)zq << 42) | sgn;
            int bz = bz_from_zq(zq);
            u32 slot = atomicAdd(&cur[bz], 1u);
            if (slot < cap) bins[slot] = ent;
        }
    }
}

// tile layout: idx = zl*4096 + bx*64 + by  (z-plane-major, bank = (by+j2)%32)
__global__ __launch_bounds__(TPB)
void bin_scatter_kernel(const u64* __restrict__ bins,
                        const u32* __restrict__ binBases,
                        int* __restrict__ partial) {
    __shared__ int tile[TILE_CELLS];   // 64 KB fixed-point accumulators
    const int slab  = blockIdx.x / G_CHUNKS;
    const int chunk = blockIdx.x - slab * G_CHUNKS;
    const int z0 = slab * SLABZ;

    for (int i = threadIdx.x; i < TILE_CELLS / 4; i += TPB)
        reinterpret_cast<int4*>(tile)[i] = make_int4(0, 0, 0, 0);
    __syncthreads();

    // entries touching slab: bz in [4s-2, 4s+3]
    int begBin = 4 * slab - 2; if (begBin < 0) begBin = 0;
    int endBin = 4 * slab + 4; if (endBin > NBINS) endBin = NBINS;
    u32 lo = binBases[begBin];
    u32 hi = binBases[endBin];
    u32 cnt = hi - lo;
    u32 per = (cnt + (u32)G_CHUNKS - 1u) / (u32)G_CHUNKS;
    u32 e0 = lo + (u32)chunk * per;
    u32 e1 = e0 + per;
    if (e1 > hi) e1 = hi;

    for (u32 e = e0 + threadIdx.x; e < e1; e += TPB) {
        u64 v = bins[e];
        float xs = (float)(u32)(v & 0x1FFFFFu) * (1.0f / 32768.0f);
        float ys = (float)(u32)((v >> 21) & 0x1FFFFFu) * (1.0f / 32768.0f);
        float zs = (float)(u32)((v >> 42) & 0x1FFFFFu) * (1.0f / 32768.0f);
        float sgn = (v >> 63) ? -1.0f : 1.0f;

        int bx = (int)(xs - 0.5f);
        int by = (int)(ys - 0.5f);
        int bz = (int)(zs - 0.5f);
        float fx = xs - (float)bx, fy = ys - (float)by, fz = zs - (float)bz;

        float wx0 = 0.5f * (1.5f - fx) * (1.5f - fx);
        float wx1 = 0.75f - (fx - 1.0f) * (fx - 1.0f);
        float wx2 = 0.5f * (fx - 0.5f) * (fx - 0.5f);
        float wy0 = 0.5f * (1.5f - fy) * (1.5f - fy);
        float wy1 = 0.75f - (fy - 1.0f) * (fy - 1.0f);
        float wy2 = 0.5f * (fy - 0.5f) * (fy - 0.5f);
        float wzv[3];
        wzv[0] = 0.5f * (1.5f - fz) * (1.5f - fz);
        wzv[1] = 0.75f - (fz - 1.0f) * (fz - 1.0f);
        wzv[2] = 0.5f * (fz - 0.5f) * (fz - 0.5f);

        float wxy[9];
        wxy[0] = sgn * wx0 * wy0; wxy[1] = sgn * wx0 * wy1; wxy[2] = sgn * wx0 * wy2;
        wxy[3] = sgn * wx1 * wy0; wxy[4] = sgn * wx1 * wy1; wxy[5] = sgn * wx1 * wy2;
        wxy[6] = sgn * wx2 * wy0; wxy[7] = sgn * wx2 * wy1; wxy[8] = sgn * wx2 * wy2;

        int basexy = bx * 64 + by;
        int zlo = bz - z0;
#pragma unroll
        for (int k = 0; k < 3; ++k) {
            int zl = zlo + k;
            if ((u32)zl < (u32)SLABZ) {
                float wzS = wzv[k] * FXS;
                int a = zl * 4096 + basexy;
#pragma unroll
                for (int i2 = 0; i2 < 3; ++i2)
#pragma unroll
                    for (int j2 = 0; j2 < 3; ++j2)
                        atomicAdd(&tile[a + i2 * 64 + j2],
                                  __float2int_rn(wxy[i2 * 3 + j2] * wzS));
            }
        }
    }
    __syncthreads();

    int* __restrict__ dst = partial + (size_t)blockIdx.x * TILE_CELLS;
    for (int i = threadIdx.x; i < TILE_CELLS / 4; i += TPB)
        reinterpret_cast<int4*>(dst)[i] = reinterpret_cast<const int4*>(tile)[i];
}

__global__ void int_reduce_kernel(const int* __restrict__ partial,
                                  float* __restrict__ out) {
    int tid = blockIdx.x * blockDim.x + threadIdx.x;   // 0 .. 262143
    int s  = tid >> 14;          // slab
    int ti = tid & 16383;        // tile cell
    const int* __restrict__ p = partial + ((size_t)s * G_CHUNKS) * TILE_CELLS + ti;
    int sum = 0;
#pragma unroll 8
    for (int g = 0; g < G_CHUNKS; ++g) sum += p[(size_t)g * TILE_CELLS];
    float v = fabsf((float)sum) * INV_FXS;
#pragma unroll
    for (int off = 32; off > 0; off >>= 1) v += __shfl_down(v, off, 64);
    __shared__ float wsum[4];
    int lane = threadIdx.x & 63, wid = threadIdx.x >> 6;
    if (lane == 0) wsum[wid] = v;
    __syncthreads();
    if (threadIdx.x == 0) atomicAdd(out, wsum[0] + wsum[1] + wsum[2] + wsum[3]);
}

// ---------------- fallback path (round-2 kernels, verified correct) --------

__global__ __launch_bounds__(TPB)
void slab_scatter_kernel(const float* __restrict__ x,
                         const float* __restrict__ xr,
                         int n, int C, float* __restrict__ partial) {
    __shared__ float tile[TILE_CELLS];
    const int slab  = blockIdx.x / C;
    const int chunk = blockIdx.x - slab * C;
    const int z0 = slab * SLABZ;

    for (int i = threadIdx.x; i < TILE_CELLS; i += TPB) tile[i] = 0.0f;
    __syncthreads();

    const int per = (n + C - 1) / C;
    const int p0 = chunk * per;
    const int p1 = min(n, p0 + per);

    for (int f = 0; f < 2; ++f) {
        const float* __restrict__ p = f ? xr : x;
        const float sgn = f ? -1.0f : 1.0f;
        for (int i = p0 + (int)threadIdx.x; i < p1; i += TPB) {
            float zs = p[3 * i + 2] * 64.0f;
            int bz = (int)floorf(zs - 0.5f);
            int zlo = bz - z0;
            if (zlo > SLABZ - 1 || zlo + 2 < 0) continue;

            float xs = p[3 * i + 0] * 64.0f;
            float ys = p[3 * i + 1] * 64.0f;
            int bx = (int)floorf(xs - 0.5f);
            int by = (int)floorf(ys - 0.5f);
            float fx = xs - (float)bx, fy = ys - (float)by, fz = zs - (float)bz;

            float wx0 = 0.5f * (1.5f - fx) * (1.5f - fx);
            float wx1 = 0.75f - (fx - 1.0f) * (fx - 1.0f);
            float wx2 = 0.5f * (fx - 0.5f) * (fx - 0.5f);
            float wy0 = 0.5f * (1.5f - fy) * (1.5f - fy);
            float wy1 = 0.75f - (fy - 1.0f) * (fy - 1.0f);
            float wy2 = 0.5f * (fy - 0.5f) * (fy - 0.5f);
            float wzv[3];
            wzv[0] = 0.5f * (1.5f - fz) * (1.5f - fz);
            wzv[1] = 0.75f - (fz - 1.0f) * (fz - 1.0f);
            wzv[2] = 0.5f * (fz - 0.5f) * (fz - 0.5f);

            float wxy[9];
            wxy[0] = sgn * wx0 * wy0; wxy[1] = sgn * wx0 * wy1; wxy[2] = sgn * wx0 * wy2;
            wxy[3] = sgn * wx1 * wy0; wxy[4] = sgn * wx1 * wy1; wxy[5] = sgn * wx1 * wy2;
            wxy[6] = sgn * wx2 * wy0; wxy[7] = sgn * wx2 * wy1; wxy[8] = sgn * wx2 * wy2;

            int base = (bx * 64 + by) * 4;
#pragma unroll
            for (int k = 0; k < 3; ++k) {
                int zl = zlo + k;
                if (zl < 0 || zl >= SLABZ) continue;
                float wzk = wzv[k];
                int a = base + zl;
#pragma unroll
                for (int i2 = 0; i2 < 3; ++i2)
#pragma unroll
                    for (int j2 = 0; j2 < 3; ++j2)
                        atomicAdd(&tile[a + i2 * 256 + j2 * 4], wxy[i2 * 3 + j2] * wzk);
            }
        }
    }
    __syncthreads();

    float* __restrict__ dst = partial + (size_t)chunk * GRID_CELLS;
    for (int t = threadIdx.x; t < NRES * NRES; t += TPB) {
        float4 v = *reinterpret_cast<const float4*>(&tile[t * 4]);
        *reinterpret_cast<float4*>(&dst[t * 64 + z0]) = v;
    }
}

__global__ void reduce_kernel(const float* __restrict__ partial, int C,
                              float* __restrict__ out) {
    int cell = blockIdx.x * blockDim.x + threadIdx.x;
    float s = 0.0f;
    for (int c = 0; c < C; ++c) s += partial[(size_t)c * GRID_CELLS + cell];
    s = fabsf(s);
#pragma unroll
    for (int off = 32; off > 0; off >>= 1) s += __shfl_down(s, off, 64);
    __shared__ float wsum[4];
    int lane = threadIdx.x & 63, wid = threadIdx.x >> 6;
    if (lane == 0) wsum[wid] = s;
    __syncthreads();
    if (threadIdx.x == 0) atomicAdd(out, wsum[0] + wsum[1] + wsum[2] + wsum[3]);
}

extern "C" void kernel_launch(void* const* d_in, const int* in_sizes, int n_in,
                              void* d_out, int out_size, void* d_ws, size_t ws_size,
                              hipStream_t stream) {
    const float* x  = (const float*)d_in[0];
    const float* xr = (const float*)d_in[1];
    float* out = (float*)d_out;
    char* ws = (char*)d_ws;

    int n = in_sizes[0] / 3;  // 4,000,000

    const size_t OFF_COUNTS = 0;
    const size_t OFF_SCAN   = (size_t)NBINS * NBLK * 4;            // 131072
    const size_t OFF_BASES  = OFF_SCAN + (size_t)NBINS * NBLK * 4; // 262144
    const size_t OFF_TOTALS = OFF_BASES + 1024;
    const size_t OFF_BINS   = OFF_BASES + 4096;                    // 266240
    const size_t binsBytes  = (size_t)(2 * n) * sizeof(u64);       // 64 MB
    const size_t OFF_PART   = OFF_BINS + binsBytes;
    const size_t partBytes  = (size_t)NSLABS * G_CHUNKS * TILE_CELLS * 4; // 32 MB
    const size_t gridBytes  = (size_t)GRID_CELLS * sizeof(float);

    hipMemsetAsync(out, 0, sizeof(float), stream);

    if ((n & 3) == 0 && ws_size >= OFF_PART + partBytes) {
        u32* blockCounts = (u32*)(ws + OFF_COUNTS);
        u32* scanned     = (u32*)(ws + OFF_SCAN);
        u32* binBases    = (u32*)(ws + OFF_BASES);
        u32* binTotals   = (u32*)(ws + OFF_TOTALS);
        u64* bins        = (u64*)(ws + OFF_BINS);
        int* partial     = (int*)(ws + OFF_PART);

        count_kernel<<<NBLK, TPB, 0, stream>>>(x, xr, n, blockCounts);
        scanA_kernel<<<NBINS, NBLK, 0, stream>>>(blockCounts, scanned, binTotals);
        scanB_kernel<<<1, 64, 0, stream>>>(binTotals, binBases);
        fill_kernel<<<NBLK, TPB, 0, stream>>>(x, xr, n, scanned, binBases, bins);
        bin_scatter_kernel<<<NSLABS * G_CHUNKS, TPB, 0, stream>>>(bins, binBases, partial);
        int_reduce_kernel<<<GRID_CELLS / 256, 256, 0, stream>>>(partial, out);
    } else {
        float* partial = (float*)ws;
        int C = (int)(ws_size / gridBytes);
        if (C > MAXC) C = MAXC;
        if (C < 1) C = 1;
        slab_scatter_kernel<<<NSLABS * C, TPB, 0, stream>>>(x, xr, n, C, partial);
        reduce_kernel<<<GRID_CELLS / 256, 256, 0, stream>>>(partial, C, out);
    }
}